// Round 1
// baseline (1951.164 us; speedup 1.0000x reference)
//
#include <hip/hip_runtime.h>

#define BATCH 8
#define NPTS  1024
#define FH    256
#define FW    256
#define FC    256
#define HID   512
#define TN    16

// ---------------------------------------------------------------------------
// Bilinear sampling: one wave (64 threads) per vertex, float4 per lane (256 ch)
// ---------------------------------------------------------------------------
__global__ __launch_bounds__(64) void sample_kernel(
    const float* __restrict__ vertices, const float* __restrict__ features,
    float* __restrict__ h0)
{
    int p = blockIdx.x;            // b*NPTS + n
    int b = p >> 10;               // NPTS = 1024
    int t = threadIdx.x;           // 0..63 -> 4 channels each

    float y = vertices[2 * p + 0];
    float x = vertices[2 * p + 1];
    float y0f = floorf(y), x0f = floorf(x);
    float wy1 = y - y0f, wx1 = x - x0f;
    float wy0 = 1.f - wy1, wx0 = 1.f - wx1;
    int y0 = (int)y0f, x0 = (int)x0f;

    float4 acc = make_float4(0.f, 0.f, 0.f, 0.f);
    const float4* fbase = (const float4*)features + (size_t)b * FH * FW * (FC / 4);

#define CORNER(yi, xi, wgt) {                                                  \
        int yy = (yi), xx = (xi);                                              \
        float wv = ((yy >= 0) && (yy < FH) && (xx >= 0) && (xx < FW)) ? (wgt) : 0.f; \
        int yc = yy < 0 ? 0 : (yy > FH - 1 ? FH - 1 : yy);                     \
        int xc = xx < 0 ? 0 : (xx > FW - 1 ? FW - 1 : xx);                     \
        float4 v = fbase[((size_t)yc * FW + xc) * (FC / 4) + t];               \
        acc.x += v.x * wv; acc.y += v.y * wv; acc.z += v.z * wv; acc.w += v.w * wv; }

    CORNER(y0,     x0,     wy0 * wx0);
    CORNER(y0,     x0 + 1, wy0 * wx1);
    CORNER(y0 + 1, x0,     wy1 * wx0);
    CORNER(y0 + 1, x0 + 1, wy1 * wx1);
#undef CORNER

    ((float4*)h0)[(size_t)p * (FC / 4) + t] = acc;
}

// ---------------------------------------------------------------------------
// Dilated K=3 Conv1D + bias + ReLU.  Block = 256 threads computes a
// [TN=16 rows x 512 cout] tile; each thread owns 2 couts for all 16 rows.
// x tile (TN + 2*rate rows x CIN) staged in dynamic LDS.
// y[n, co] = relu(b[co] + sum_k sum_ci x[n + (k-1)*rate, ci] * w[k, ci, co])
// ---------------------------------------------------------------------------
template <int CIN>
__global__ __launch_bounds__(256) void conv1d_relu_kernel(
    const float* __restrict__ x, const float* __restrict__ w,
    const float* __restrict__ bias, float* __restrict__ y, int rate)
{
    extern __shared__ float xs[];
    const int tid  = threadIdx.x;
    const int b    = blockIdx.x / (NPTS / TN);
    const int n0   = (blockIdx.x % (NPTS / TN)) * TN;
    const int rows = TN + 2 * rate;

    // ---- stage x tile (zero-padded outside [0, NPTS)) ----
    const float4* x4  = (const float4*)(x + (size_t)b * NPTS * CIN);
    float4*       xs4 = (float4*)xs;
    const int total4  = rows * (CIN / 4);
    for (int i = tid; i < total4; i += 256) {
        int r = i / (CIN / 4);
        int c = i - r * (CIN / 4);
        int g = n0 - rate + r;
        float4 v = make_float4(0.f, 0.f, 0.f, 0.f);
        if (g >= 0 && g < NPTS) v = x4[(size_t)g * (CIN / 4) + c];
        xs4[i] = v;
    }
    __syncthreads();

    // ---- accumulate: thread owns couts {2*tid, 2*tid+1} ----
    float2 bv = *(const float2*)(bias + 2 * tid);
    float2 acc[TN];
#pragma unroll
    for (int n = 0; n < TN; ++n) acc[n] = bv;

    for (int k = 0; k < 3; ++k) {
        const float* wk   = w + (size_t)k * CIN * HID + 2 * tid;
        const float* xrow = xs + k * rate * CIN;   // local row for out n, tap k = n + k*rate
        for (int ci = 0; ci < CIN; ci += 4) {
            float2 w0v = *(const float2*)(wk + (size_t)(ci + 0) * HID);
            float2 w1v = *(const float2*)(wk + (size_t)(ci + 1) * HID);
            float2 w2v = *(const float2*)(wk + (size_t)(ci + 2) * HID);
            float2 w3v = *(const float2*)(wk + (size_t)(ci + 3) * HID);
#pragma unroll
            for (int n = 0; n < TN; ++n) {
                float4 xv = *(const float4*)(xrow + n * CIN + ci);
                acc[n].x += xv.x * w0v.x + xv.y * w1v.x + xv.z * w2v.x + xv.w * w3v.x;
                acc[n].y += xv.x * w0v.y + xv.y * w1v.y + xv.z * w2v.y + xv.w * w3v.y;
            }
        }
    }

    // ---- ReLU + store ----
    float* yout = y + ((size_t)b * NPTS + n0) * HID + 2 * tid;
#pragma unroll
    for (int n = 0; n < TN; ++n) {
        float a0 = acc[n].x > 0.f ? acc[n].x : 0.f;
        float a1 = acc[n].y > 0.f ? acc[n].y : 0.f;
        *(float2*)(yout + (size_t)n * HID) = make_float2(a0, a1);
    }
}

// ---------------------------------------------------------------------------
// Offset head: out[p, :] = vertices[p, :] + h[p, :] @ w_off   (512 -> 2)
// One wave per vertex; lane t covers ci = 8t..8t+7; shuffle-reduce.
// ---------------------------------------------------------------------------
__global__ __launch_bounds__(64) void head_kernel(
    const float* __restrict__ h, const float* __restrict__ w_off,
    const float* __restrict__ vertices, float* __restrict__ out)
{
    int p = blockIdx.x;
    int t = threadIdx.x;  // 0..63
    const float4* h4 = (const float4*)(h + (size_t)p * HID);
    const float4* w4 = (const float4*)w_off;   // [HID][2] -> float4 covers 2 ci

    float s0 = 0.f, s1 = 0.f;
#pragma unroll
    for (int q = 0; q < 2; ++q) {
        float4 hv = h4[t * 2 + q];
        int ci0   = t * 8 + q * 4;
        float4 A  = w4[ci0 / 2];       // (ci0,0)(ci0,1)(ci0+1,0)(ci0+1,1)
        float4 Bv = w4[ci0 / 2 + 1];   // (ci0+2,0)(ci0+2,1)(ci0+3,0)(ci0+3,1)
        s0 += hv.x * A.x + hv.y * A.z + hv.z * Bv.x + hv.w * Bv.z;
        s1 += hv.x * A.y + hv.y * A.w + hv.z * Bv.y + hv.w * Bv.w;
    }
#pragma unroll
    for (int off = 32; off >= 1; off >>= 1) {
        s0 += __shfl_down(s0, off);
        s1 += __shfl_down(s1, off);
    }
    if (t == 0) {
        out[2 * p + 0] = vertices[2 * p + 0] + s0;
        out[2 * p + 1] = vertices[2 * p + 1] + s1;
    }
}

// ---------------------------------------------------------------------------
extern "C" void kernel_launch(void* const* d_in, const int* in_sizes, int n_in,
                              void* d_out, int out_size, void* d_ws, size_t ws_size,
                              hipStream_t stream)
{
    (void)in_sizes; (void)n_in; (void)out_size; (void)ws_size;

    const float* vertices = (const float*)d_in[0];
    const float* features = (const float*)d_in[1];
    const float* w[6]  = {(const float*)d_in[2], (const float*)d_in[4],
                          (const float*)d_in[6], (const float*)d_in[8],
                          (const float*)d_in[10], (const float*)d_in[12]};
    const float* bb[6] = {(const float*)d_in[3], (const float*)d_in[5],
                          (const float*)d_in[7], (const float*)d_in[9],
                          (const float*)d_in[11], (const float*)d_in[13]};
    const float* w_off = (const float*)d_in[14];
    float* out = (float*)d_out;

    // workspace layout: h0 (8 MB) | bufA (16 MB) | bufB (16 MB)
    float* h0   = (float*)d_ws;
    float* bufA = h0 + (size_t)BATCH * NPTS * FC;
    float* bufB = bufA + (size_t)BATCH * NPTS * HID;

    // 1) bilinear sampling -> h0 [B, N, 256]
    sample_kernel<<<BATCH * NPTS, 64, 0, stream>>>(vertices, features, h0);

    // 2) conv stack
    static const int rates[6] = {1, 3, 9, 9, 3, 1};
    {
        size_t lds = (size_t)(TN + 2 * rates[0]) * FC * sizeof(float);
        conv1d_relu_kernel<FC><<<BATCH * (NPTS / TN), 256, lds, stream>>>(
            h0, w[0], bb[0], bufA, rates[0]);
    }
    const float* src = bufA;
    float*       dst = bufB;
    for (int i = 1; i < 6; ++i) {
        size_t lds = (size_t)(TN + 2 * rates[i]) * HID * sizeof(float);
        conv1d_relu_kernel<HID><<<BATCH * (NPTS / TN), 256, lds, stream>>>(
            src, w[i], bb[i], dst, rates[i]);
        float* tmp = (float*)src; src = dst; dst = tmp;
    }

    // 3) offset head + residual add -> out [B, N, 2]
    head_kernel<<<BATCH * NPTS, 64, 0, stream>>>(src, w_off, vertices, out);
}

// Round 2
// 154.727 us; speedup vs baseline: 12.6104x; 12.6104x over previous
//
#include <hip/hip_runtime.h>

#define BATCH 8
#define NPTS  1024
#define FH    256
#define FW    256
#define FC    256
#define HID   512
#define PADN  1056          // 16-row halo each side (rate <= 9)
#define HALO  16

typedef __attribute__((ext_vector_type(8))) short short8;
typedef __attribute__((ext_vector_type(16))) float f32x16;
typedef unsigned short ushort_t;
typedef unsigned int uint_t;

__device__ __forceinline__ ushort_t f2bf(float f) {
    uint_t u = __builtin_bit_cast(uint_t, f);
    u += 0x7fffu + ((u >> 16) & 1u);          // round-to-nearest-even
    return (ushort_t)(u >> 16);
}
__device__ __forceinline__ float bf2f(ushort_t s) {
    uint_t u = ((uint_t)s) << 16;
    return __builtin_bit_cast(float, u);
}

#define GLOAD16(g, l)                                                     \
    __builtin_amdgcn_global_load_lds(                                     \
        (const __attribute__((address_space(1))) void*)(g),               \
        (__attribute__((address_space(3))) void*)(l), 16, 0, 0)

// ---------------------------------------------------------------------------
// Zero the 16-row halos of the three padded activation buffers.
// ---------------------------------------------------------------------------
__global__ __launch_bounds__(256) void halo_zero(
    ushort_t* __restrict__ XpA, ushort_t* __restrict__ XpB, ushort_t* __restrict__ XpC)
{
    int i = blockIdx.x * 256 + threadIdx.x;
    if (i < 65536) {                       // A: 8 * 2 strips * 16*256
        int b = i >> 13, rem = i & 8191;
        int strip = rem >> 12, off = rem & 4095;
        XpA[(size_t)b * (PADN * FC) + (strip ? (PADN - HALO) * FC : 0) + off] = 0;
    }
    int jB = i - 65536;                    // B,C: 8 * 2 strips * 16*512 each
    if (jB >= 0 && jB < 262144) {
        ushort_t* T = (jB < 131072) ? XpB : XpC;
        int j = jB & 131071;
        int b = j >> 14, rem = j & 16383;
        int strip = rem >> 13, off = rem & 8191;
        T[(size_t)b * (PADN * HID) + (strip ? (PADN - HALO) * HID : 0) + off] = 0;
    }
}

// ---------------------------------------------------------------------------
// Weight prep: w [3][CIN][512] fp32  ->  Wt [512][3*CIN] bf16 (transposed)
// grid (3*CIN/64, 512/64), block 256. LDS 64x65 tile transpose.
// ---------------------------------------------------------------------------
__global__ __launch_bounds__(256) void wprep_kernel(
    const float* __restrict__ w, ushort_t* __restrict__ wt, int CIN)
{
    __shared__ float tile[64][65];
    int t = threadIdx.x;
    int kk0 = blockIdx.x * 64, co0 = blockIdx.y * 64;
    int tap = kk0 / CIN, ci0 = kk0 - tap * CIN;
    int K3 = 3 * CIN;
#pragma unroll 4
    for (int it = 0; it < 16; ++it) {
        int r = it * 4 + (t >> 6);
        tile[r][t & 63] = w[((size_t)tap * CIN + ci0 + r) * HID + co0 + (t & 63)];
    }
    __syncthreads();
#pragma unroll 4
    for (int it = 0; it < 16; ++it) {
        int co = it * 4 + (t >> 6);
        wt[(size_t)(co0 + co) * K3 + kk0 + (t & 63)] = f2bf(tile[t & 63][co]);
    }
}

// ---------------------------------------------------------------------------
// Bilinear sampling -> padded bf16 XpA [8][1056][256]
// ---------------------------------------------------------------------------
__global__ __launch_bounds__(64) void sample_kernel(
    const float* __restrict__ vertices, const float* __restrict__ features,
    ushort_t* __restrict__ XpA)
{
    int p = blockIdx.x;            // b*NPTS + n
    int b = p >> 10;
    int n = p & 1023;
    int t = threadIdx.x;           // 0..63 -> 4 channels each

    float y = vertices[2 * p + 0];
    float x = vertices[2 * p + 1];
    float y0f = floorf(y), x0f = floorf(x);
    float wy1 = y - y0f, wx1 = x - x0f;
    float wy0 = 1.f - wy1, wx0 = 1.f - wx1;
    int y0 = (int)y0f, x0 = (int)x0f;

    float4 acc = make_float4(0.f, 0.f, 0.f, 0.f);
    const float4* fbase = (const float4*)features + (size_t)b * FH * FW * (FC / 4);

#define CORNER(yi, xi, wgt) {                                                  \
        int yy = (yi), xx = (xi);                                              \
        float wv = ((yy >= 0) && (yy < FH) && (xx >= 0) && (xx < FW)) ? (wgt) : 0.f; \
        int yc = yy < 0 ? 0 : (yy > FH - 1 ? FH - 1 : yy);                     \
        int xc = xx < 0 ? 0 : (xx > FW - 1 ? FW - 1 : xx);                     \
        float4 v = fbase[((size_t)yc * FW + xc) * (FC / 4) + t];               \
        acc.x += v.x * wv; acc.y += v.y * wv; acc.z += v.z * wv; acc.w += v.w * wv; }

    CORNER(y0,     x0,     wy0 * wx0);
    CORNER(y0,     x0 + 1, wy0 * wx1);
    CORNER(y0 + 1, x0,     wy1 * wx0);
    CORNER(y0 + 1, x0 + 1, wy1 * wx1);
#undef CORNER

    ushort4 o;
    o.x = f2bf(acc.x); o.y = f2bf(acc.y); o.z = f2bf(acc.z); o.w = f2bf(acc.w);
    *(ushort4*)(XpA + ((size_t)b * PADN + HALO + n) * FC + 4 * t) = o;
}

// ---------------------------------------------------------------------------
// Dilated conv as MFMA GEMM.
//   Y[m, co] = relu(bias[co] + sum_kk A[m, kk] * Wt[co, kk]),
//   A[m, tap*CIN+ci] = Xp[m + (tap-1)*rate, ci]  (padded rows, halos zero)
// Block: 256 thr (4 waves, 2x2), tile 128x128, wave tile 64x64 (2x2 frags of
// 32x32x16). BK=64, double-buffered LDS, 2-phase prefetch, XOR chunk swizzle.
// ---------------------------------------------------------------------------
template <int CIN>
__global__ __launch_bounds__(256) void conv_mfma(
    const ushort_t* __restrict__ Xp,   // [8][1056][CIN] bf16
    const ushort_t* __restrict__ Wt,   // [512][3*CIN]  bf16
    const float* __restrict__ bias,    // [512] fp32
    ushort_t* __restrict__ Yp,         // [8][1056][512] bf16 (interior write)
    int rate)
{
    constexpr int K3 = 3 * CIN;
    constexpr int NT = K3 / 64;        // K-steps
    __shared__ short lds[2][16384];    // [buf][A(8192) | B(8192)] shorts

    const int tid  = threadIdx.x;
    const int wid  = tid >> 6;
    const int lane = tid & 63;
    const int wm   = wid >> 1, wn = wid & 1;

    const int bm    = blockIdx.x;          // 0..63
    const int bn    = blockIdx.y;          // 0..3
    const int batch = bm >> 3;
    const int n0    = (bm & 7) * 128;
    const int co0   = bn * 128;

    const short* Xbase = (const short*)Xp + ((size_t)batch * PADN + HALO + n0) * CIN;
    const short* Wbase = (const short*)Wt + (size_t)co0 * K3;

    // ---- staging: one K-step = A[128][64] + B[128][64] bf16 tiles ----
    auto stage = [&](int buf, int kt) {
        const int tap = (kt << 6) / CIN;
        const int ci0 = (kt << 6) - tap * CIN;
        const short* Ag = Xbase + (ptrdiff_t)(tap - 1) * rate * CIN + ci0;
        const short* Bg = Wbase + (kt << 6);
        short* ldsA = &lds[buf][0];
        short* ldsB = &lds[buf][8192];
#pragma unroll
        for (int it = 0; it < 4; ++it) {
            int rb   = (wid * 4 + it) << 3;              // row base (mult of 8)
            int row  = rb + (lane >> 3);
            int chnk = (lane & 7) ^ (row & 7);           // inverse swizzle on src
            GLOAD16(Ag + (size_t)row * CIN + chnk * 8, ldsA + ((wid * 4 + it) << 9));
            GLOAD16(Bg + (size_t)row * K3  + chnk * 8, ldsB + ((wid * 4 + it) << 9));
        }
    };

    // ---- accumulators init with bias ----
    f32x16 acc[2][2];
    const int rowA0 = wm * 64 + (lane & 31);
    const int rowB0 = wn * 64 + (lane & 31);
#pragma unroll
    for (int j = 0; j < 2; ++j) {
        float bv = bias[co0 + wn * 64 + j * 32 + (lane & 31)];
#pragma unroll
        for (int i = 0; i < 2; ++i)
#pragma unroll
            for (int r = 0; r < 16; ++r) acc[i][j][r] = bv;
    }

    stage(0, 0);
    asm volatile("s_waitcnt vmcnt(0)" ::: "memory");
    __syncthreads();

    int cur = 0;
    for (int kt = 0; kt < NT; ++kt) {
        if (kt + 1 < NT) stage(cur ^ 1, kt + 1);

        const short* As = &lds[cur][0];
        const short* Bs = &lds[cur][8192];
#pragma unroll
        for (int ks = 0; ks < 4; ++ks) {
            int ch = ks * 2 + (lane >> 5);
            short8 av[2], bv[2];
#pragma unroll
            for (int i = 0; i < 2; ++i) {
                int ra = rowA0 + i * 32;
                av[i] = *(const short8*)(As + ra * 64 + ((ch ^ (ra & 7)) << 3));
            }
#pragma unroll
            for (int j = 0; j < 2; ++j) {
                int rb = rowB0 + j * 32;
                bv[j] = *(const short8*)(Bs + rb * 64 + ((ch ^ (rb & 7)) << 3));
            }
#pragma unroll
            for (int i = 0; i < 2; ++i)
#pragma unroll
                for (int j = 0; j < 2; ++j)
                    acc[i][j] = __builtin_amdgcn_mfma_f32_32x32x16_bf16(
                        av[i], bv[j], acc[i][j], 0, 0, 0);
        }
        __syncthreads();
        cur ^= 1;
    }

    // ---- epilogue: ReLU + bf16 store into padded interior ----
    ushort_t* Yb = Yp + ((size_t)batch * PADN + HALO + n0) * HID + co0;
#pragma unroll
    for (int i = 0; i < 2; ++i)
#pragma unroll
        for (int j = 0; j < 2; ++j) {
            int cco = wn * 64 + j * 32 + (lane & 31);
#pragma unroll
            for (int r = 0; r < 16; ++r) {
                int rrow = wm * 64 + i * 32 + (r & 3) + 8 * (r >> 2) + 4 * (lane >> 5);
                float v = acc[i][j][r];
                v = v > 0.f ? v : 0.f;
                Yb[(size_t)rrow * HID + cco] = f2bf(v);
            }
        }
}

// ---------------------------------------------------------------------------
// Offset head: out[p,:] = vertices[p,:] + h[p,:] @ w_off  (bf16 h, fp32 w)
// ---------------------------------------------------------------------------
__global__ __launch_bounds__(64) void head_kernel(
    const ushort_t* __restrict__ h, const float* __restrict__ w_off,
    const float* __restrict__ vertices, float* __restrict__ out)
{
    int p = blockIdx.x;
    int b = p >> 10, n = p & 1023;
    int t = threadIdx.x;
    const ushort_t* hr = h + ((size_t)b * PADN + HALO + n) * HID + t * 8;

    uint4 raw = *(const uint4*)hr;
    ushort_t hv[8];
    hv[0] = raw.x & 0xffff; hv[1] = raw.x >> 16;
    hv[2] = raw.y & 0xffff; hv[3] = raw.y >> 16;
    hv[4] = raw.z & 0xffff; hv[5] = raw.z >> 16;
    hv[6] = raw.w & 0xffff; hv[7] = raw.w >> 16;

    float s0 = 0.f, s1 = 0.f;
#pragma unroll
    for (int k = 0; k < 8; ++k) {
        float x = bf2f(hv[k]);
        s0 += x * w_off[(t * 8 + k) * 2 + 0];
        s1 += x * w_off[(t * 8 + k) * 2 + 1];
    }
#pragma unroll
    for (int off = 32; off >= 1; off >>= 1) {
        s0 += __shfl_down(s0, off);
        s1 += __shfl_down(s1, off);
    }
    if (t == 0) {
        out[2 * p + 0] = vertices[2 * p + 0] + s0;
        out[2 * p + 1] = vertices[2 * p + 1] + s1;
    }
}

// ---------------------------------------------------------------------------
extern "C" void kernel_launch(void* const* d_in, const int* in_sizes, int n_in,
                              void* d_out, int out_size, void* d_ws, size_t ws_size,
                              hipStream_t stream)
{
    (void)in_sizes; (void)n_in; (void)out_size; (void)ws_size;

    const float* vertices = (const float*)d_in[0];
    const float* features = (const float*)d_in[1];
    const float* w[6]  = {(const float*)d_in[2], (const float*)d_in[4],
                          (const float*)d_in[6], (const float*)d_in[8],
                          (const float*)d_in[10], (const float*)d_in[12]};
    const float* bb[6] = {(const float*)d_in[3], (const float*)d_in[5],
                          (const float*)d_in[7], (const float*)d_in[9],
                          (const float*)d_in[11], (const float*)d_in[13]};
    const float* w_off = (const float*)d_in[14];
    float* out = (float*)d_out;

    // ---- workspace layout (bytes) ----
    char* p = (char*)d_ws;
    ushort_t* wt[6];
    wt[0] = (ushort_t*)p; p += (size_t)HID * (3 * FC) * 2;          // 768 KB
    for (int i = 1; i < 6; ++i) { wt[i] = (ushort_t*)p; p += (size_t)HID * (3 * HID) * 2; }
    ushort_t* XpA = (ushort_t*)p; p += (size_t)BATCH * PADN * FC  * 2;
    ushort_t* XpB = (ushort_t*)p; p += (size_t)BATCH * PADN * HID * 2;
    ushort_t* XpC = (ushort_t*)p;

    // ---- prep ----
    halo_zero<<<1280, 256, 0, stream>>>(XpA, XpB, XpC);
    wprep_kernel<<<dim3(3 * FC / 64, HID / 64), 256, 0, stream>>>(w[0], wt[0], FC);
    for (int i = 1; i < 6; ++i)
        wprep_kernel<<<dim3(3 * HID / 64, HID / 64), 256, 0, stream>>>(w[i], wt[i], HID);

    // ---- sampling ----
    sample_kernel<<<BATCH * NPTS, 64, 0, stream>>>(vertices, features, XpA);

    // ---- conv stack (A -> B -> C -> B -> C -> B -> C) ----
    static const int rates[6] = {1, 3, 9, 9, 3, 1};
    conv_mfma<FC><<<dim3(64, 4), 256, 0, stream>>>(XpA, wt[0], bb[0], XpB, rates[0]);
    ushort_t* src = XpB;
    ushort_t* dst = XpC;
    for (int i = 1; i < 6; ++i) {
        conv_mfma<HID><<<dim3(64, 4), 256, 0, stream>>>(src, wt[i], bb[i], dst, rates[i]);
        ushort_t* tmp = src; src = dst; dst = tmp;
    }
    // after loop, final output is in `src`

    // ---- head ----
    head_kernel<<<BATCH * NPTS, 64, 0, stream>>>(src, w_off, vertices, out);
}

// Round 3
// 126.085 us; speedup vs baseline: 15.4750x; 1.2272x over previous
//
#include <hip/hip_runtime.h>

#define BATCH 8
#define NPTS  1024
#define FH    256
#define FW    256
#define FC    256
#define HID   512
#define PADN  1056          // 16-row halo each side (rate <= 9)
#define HALO  16

typedef __attribute__((ext_vector_type(8))) short short8;
typedef __attribute__((ext_vector_type(16))) float f32x16;
typedef unsigned short ushort_t;
typedef unsigned int uint_t;

__device__ __forceinline__ ushort_t f2bf(float f) {
    uint_t u = __builtin_bit_cast(uint_t, f);
    u += 0x7fffu + ((u >> 16) & 1u);          // round-to-nearest-even
    return (ushort_t)(u >> 16);
}
__device__ __forceinline__ float bf2f(ushort_t s) {
    uint_t u = ((uint_t)s) << 16;
    return __builtin_bit_cast(float, u);
}

#define GLOAD16(g, l)                                                     \
    __builtin_amdgcn_global_load_lds(                                     \
        (const __attribute__((address_space(1))) void*)(g),               \
        (__attribute__((address_space(3))) void*)(l), 16, 0, 0)

// ---------------------------------------------------------------------------
// Fused prep kernel: [0,1280) halo zeroing, [1280,2336) weight transpose,
// [2336,4384) bilinear sampling (4 vertices per block).
// ---------------------------------------------------------------------------
__global__ __launch_bounds__(256) void prep_kernel(
    const float* __restrict__ vertices, const float* __restrict__ features,
    const float* __restrict__ w0, const float* __restrict__ w1,
    const float* __restrict__ w2, const float* __restrict__ w3,
    const float* __restrict__ w4, const float* __restrict__ w5,
    ushort_t* __restrict__ wt0, ushort_t* __restrict__ wt1,
    ushort_t* __restrict__ wt2, ushort_t* __restrict__ wt3,
    ushort_t* __restrict__ wt4, ushort_t* __restrict__ wt5,
    ushort_t* __restrict__ XpA, ushort_t* __restrict__ XpB,
    ushort_t* __restrict__ XpC)
{
    __shared__ float tile[64][65];
    const int blk = blockIdx.x;
    const int tid = threadIdx.x;

    if (blk < 1280) {
        // ---- halo zeroing ----
        int i = blk * 256 + tid;
        if (i < 65536) {                   // A halos: 8 * 2 strips * 16*256
            int b = i >> 13, rem = i & 8191;
            int strip = rem >> 12, off = rem & 4095;
            XpA[(size_t)b * (PADN * FC) + (strip ? (PADN - HALO) * FC : 0) + off] = 0;
        }
        int jB = i - 65536;                // B,C halos: 8 * 2 strips * 16*512
        if (jB >= 0 && jB < 262144) {
            ushort_t* T = (jB < 131072) ? XpB : XpC;
            int j = jB & 131071;
            int b = j >> 14, rem = j & 16383;
            int strip = rem >> 13, off = rem & 8191;
            T[(size_t)b * (PADN * HID) + (strip ? (PADN - HALO) * HID : 0) + off] = 0;
        }
        return;
    }

    if (blk < 2336) {
        // ---- weight transpose: w [3][CIN][512] fp32 -> wt [512][3*CIN] bf16 ----
        int j = blk - 1280;
        const float* w; ushort_t* wt; int CIN, kk0, co0;
        if (j < 96) {
            w = w0; wt = wt0; CIN = FC;
            kk0 = (j % 12) * 64; co0 = (j / 12) * 64;
        } else {
            int j2 = j - 96;
            int layer = j2 / 192, jj = j2 % 192;
            const float* ws[5]  = {w1, w2, w3, w4, w5};
            ushort_t*   wts[5]  = {wt1, wt2, wt3, wt4, wt5};
            w = ws[layer]; wt = wts[layer]; CIN = HID;
            kk0 = (jj % 24) * 64; co0 = (jj / 24) * 64;
        }
        int tap = kk0 / CIN, ci0 = kk0 - tap * CIN;
        int K3 = 3 * CIN;
#pragma unroll 4
        for (int it = 0; it < 16; ++it) {
            int r = it * 4 + (tid >> 6);
            tile[r][tid & 63] = w[((size_t)tap * CIN + ci0 + r) * HID + co0 + (tid & 63)];
        }
        __syncthreads();
#pragma unroll 4
        for (int it = 0; it < 16; ++it) {
            int co = it * 4 + (tid >> 6);
            wt[(size_t)(co0 + co) * K3 + kk0 + (tid & 63)] = f2bf(tile[tid & 63][co]);
        }
        return;
    }

    // ---- bilinear sampling: 4 vertices per block ----
    {
        int p = (blk - 2336) * 4 + (tid >> 6);   // b*NPTS + n
        int b = p >> 10;
        int n = p & 1023;
        int t = tid & 63;                        // 4 channels each

        float y = vertices[2 * p + 0];
        float x = vertices[2 * p + 1];
        float y0f = floorf(y), x0f = floorf(x);
        float wy1 = y - y0f, wx1 = x - x0f;
        float wy0 = 1.f - wy1, wx0 = 1.f - wx1;
        int y0 = (int)y0f, x0 = (int)x0f;

        float4 acc = make_float4(0.f, 0.f, 0.f, 0.f);
        const float4* fbase = (const float4*)features + (size_t)b * FH * FW * (FC / 4);

#define CORNER(yi, xi, wgt) {                                                  \
        int yy = (yi), xx = (xi);                                              \
        float wv = ((yy >= 0) && (yy < FH) && (xx >= 0) && (xx < FW)) ? (wgt) : 0.f; \
        int yc = yy < 0 ? 0 : (yy > FH - 1 ? FH - 1 : yy);                     \
        int xc = xx < 0 ? 0 : (xx > FW - 1 ? FW - 1 : xx);                     \
        float4 v = fbase[((size_t)yc * FW + xc) * (FC / 4) + t];               \
        acc.x += v.x * wv; acc.y += v.y * wv; acc.z += v.z * wv; acc.w += v.w * wv; }

        CORNER(y0,     x0,     wy0 * wx0);
        CORNER(y0,     x0 + 1, wy0 * wx1);
        CORNER(y0 + 1, x0,     wy1 * wx0);
        CORNER(y0 + 1, x0 + 1, wy1 * wx1);
#undef CORNER

        ushort4 o;
        o.x = f2bf(acc.x); o.y = f2bf(acc.y); o.z = f2bf(acc.z); o.w = f2bf(acc.w);
        *(ushort4*)(XpA + ((size_t)b * PADN + HALO + n) * FC + 4 * t) = o;
    }
}

// ---------------------------------------------------------------------------
// Dilated conv as MFMA GEMM, tile 128x64 (M x CO), 4 waves (2x2),
// wave tile 64x32 (2x1 frags of 32x32x16). BK=64, double-buffered LDS,
// XOR chunk swizzle. Grid 512 flat with XCD-aware decode: the 8 co-blocks of
// one m-panel land on one XCD (h%8 round-robin) -> A-panel L2-resident.
// ---------------------------------------------------------------------------
template <int CIN>
__global__ __launch_bounds__(256) void conv_mfma(
    const ushort_t* __restrict__ Xp,   // [8][1056][CIN] bf16
    const ushort_t* __restrict__ Wt,   // [512][3*CIN]  bf16
    const float* __restrict__ bias,    // [512] fp32
    ushort_t* __restrict__ Yp,         // [8][1056][512] bf16 (interior write)
    int rate)
{
    constexpr int K3 = 3 * CIN;
    constexpr int NT = K3 / 64;        // K-steps
    __shared__ short lds[2][12288];    // [buf][A(8192) | B(4096)] shorts

    const int tid  = threadIdx.x;
    const int wid  = tid >> 6;
    const int lane = tid & 63;
    const int wm   = wid >> 1, wn = wid & 1;

    const int h  = blockIdx.x;               // 0..511
    const int bm = (h & 7) * 8 + (h >> 6);   // 0..63  (XCD h%8 gets bm-group)
    const int bn = (h >> 3) & 7;             // 0..7
    const int batch = bm >> 3;
    const int n0    = (bm & 7) * 128;
    const int co0   = bn * 64;

    const short* Xbase = (const short*)Xp + ((size_t)batch * PADN + HALO + n0) * CIN;
    const short* Wbase = (const short*)Wt + (size_t)co0 * K3;

    // ---- staging: one K-step = A[128][64] + B[64][64] bf16 tiles ----
    auto stage = [&](int buf, int kt) {
        const int tap = (kt << 6) / CIN;
        const int ci0 = (kt << 6) - tap * CIN;
        const short* Ag = Xbase + (ptrdiff_t)(tap - 1) * rate * CIN + ci0;
        const short* Bg = Wbase + (kt << 6);
        short* ldsA = &lds[buf][0];
        short* ldsB = &lds[buf][8192];
#pragma unroll
        for (int it = 0; it < 4; ++it) {          // A: wave covers rows wid*32..+31
            int row  = wid * 32 + it * 8 + (lane >> 3);
            int chnk = (lane & 7) ^ (row & 7);    // inverse swizzle on src
            GLOAD16(Ag + (size_t)row * CIN + chnk * 8, ldsA + ((wid * 4 + it) << 9));
        }
#pragma unroll
        for (int it = 0; it < 2; ++it) {          // B: wave covers rows wid*16..+15
            int row  = wid * 16 + it * 8 + (lane >> 3);
            int chnk = (lane & 7) ^ (row & 7);
            GLOAD16(Bg + (size_t)row * K3 + chnk * 8, ldsB + ((wid * 2 + it) << 9));
        }
    };

    // ---- accumulators init with bias ----
    f32x16 acc[2];
    const int rowA0 = wm * 64 + (lane & 31);
    const int coB   = wn * 32 + (lane & 31);
    {
        float bv = bias[co0 + coB];
#pragma unroll
        for (int i = 0; i < 2; ++i)
#pragma unroll
            for (int r = 0; r < 16; ++r) acc[i][r] = bv;
    }

    stage(0, 0);
    asm volatile("s_waitcnt vmcnt(0)" ::: "memory");
    __syncthreads();

    int cur = 0;
    for (int kt = 0; kt < NT; ++kt) {
        if (kt + 1 < NT) stage(cur ^ 1, kt + 1);

        const short* As = &lds[cur][0];
        const short* Bs = &lds[cur][8192];
#pragma unroll
        for (int ks = 0; ks < 4; ++ks) {
            int ch = ks * 2 + (lane >> 5);
            short8 av[2], bv;
#pragma unroll
            for (int i = 0; i < 2; ++i) {
                int ra = rowA0 + i * 32;
                av[i] = *(const short8*)(As + ra * 64 + ((ch ^ (ra & 7)) << 3));
            }
            bv = *(const short8*)(Bs + coB * 64 + ((ch ^ (coB & 7)) << 3));
#pragma unroll
            for (int i = 0; i < 2; ++i)
                acc[i] = __builtin_amdgcn_mfma_f32_32x32x16_bf16(
                    av[i], bv, acc[i], 0, 0, 0);
        }
        __syncthreads();
        cur ^= 1;
    }

    // ---- epilogue: ReLU + bf16 store into padded interior ----
    ushort_t* Yb = Yp + ((size_t)batch * PADN + HALO + n0) * HID + co0;
#pragma unroll
    for (int i = 0; i < 2; ++i) {
#pragma unroll
        for (int r = 0; r < 16; ++r) {
            int rrow = wm * 64 + i * 32 + (r & 3) + 8 * (r >> 2) + 4 * (lane >> 5);
            float v = acc[i][r];
            v = v > 0.f ? v : 0.f;
            Yb[(size_t)rrow * HID + coB] = f2bf(v);
        }
    }
}

// ---------------------------------------------------------------------------
// Offset head: out[p,:] = vertices[p,:] + h[p,:] @ w_off  (bf16 h, fp32 w)
// ---------------------------------------------------------------------------
__global__ __launch_bounds__(64) void head_kernel(
    const ushort_t* __restrict__ h, const float* __restrict__ w_off,
    const float* __restrict__ vertices, float* __restrict__ out)
{
    int p = blockIdx.x;
    int b = p >> 10, n = p & 1023;
    int t = threadIdx.x;
    const ushort_t* hr = h + ((size_t)b * PADN + HALO + n) * HID + t * 8;

    uint4 raw = *(const uint4*)hr;
    ushort_t hv[8];
    hv[0] = raw.x & 0xffff; hv[1] = raw.x >> 16;
    hv[2] = raw.y & 0xffff; hv[3] = raw.y >> 16;
    hv[4] = raw.z & 0xffff; hv[5] = raw.z >> 16;
    hv[6] = raw.w & 0xffff; hv[7] = raw.w >> 16;

    float s0 = 0.f, s1 = 0.f;
#pragma unroll
    for (int k = 0; k < 8; ++k) {
        float x = bf2f(hv[k]);
        s0 += x * w_off[(t * 8 + k) * 2 + 0];
        s1 += x * w_off[(t * 8 + k) * 2 + 1];
    }
#pragma unroll
    for (int off = 32; off >= 1; off >>= 1) {
        s0 += __shfl_down(s0, off);
        s1 += __shfl_down(s1, off);
    }
    if (t == 0) {
        out[2 * p + 0] = vertices[2 * p + 0] + s0;
        out[2 * p + 1] = vertices[2 * p + 1] + s1;
    }
}

// ---------------------------------------------------------------------------
extern "C" void kernel_launch(void* const* d_in, const int* in_sizes, int n_in,
                              void* d_out, int out_size, void* d_ws, size_t ws_size,
                              hipStream_t stream)
{
    (void)in_sizes; (void)n_in; (void)out_size; (void)ws_size;

    const float* vertices = (const float*)d_in[0];
    const float* features = (const float*)d_in[1];
    const float* w[6]  = {(const float*)d_in[2], (const float*)d_in[4],
                          (const float*)d_in[6], (const float*)d_in[8],
                          (const float*)d_in[10], (const float*)d_in[12]};
    const float* bb[6] = {(const float*)d_in[3], (const float*)d_in[5],
                          (const float*)d_in[7], (const float*)d_in[9],
                          (const float*)d_in[11], (const float*)d_in[13]};
    const float* w_off = (const float*)d_in[14];
    float* out = (float*)d_out;

    // ---- workspace layout ----
    char* p = (char*)d_ws;
    ushort_t* wt[6];
    wt[0] = (ushort_t*)p; p += (size_t)HID * (3 * FC) * 2;          // 768 KB
    for (int i = 1; i < 6; ++i) { wt[i] = (ushort_t*)p; p += (size_t)HID * (3 * HID) * 2; }
    ushort_t* XpA = (ushort_t*)p; p += (size_t)BATCH * PADN * FC  * 2;
    ushort_t* XpB = (ushort_t*)p; p += (size_t)BATCH * PADN * HID * 2;
    ushort_t* XpC = (ushort_t*)p;

    // ---- fused prep: halos + weight transpose + sampling ----
    prep_kernel<<<4384, 256, 0, stream>>>(
        vertices, features, w[0], w[1], w[2], w[3], w[4], w[5],
        wt[0], wt[1], wt[2], wt[3], wt[4], wt[5], XpA, XpB, XpC);

    // ---- conv stack (A -> B -> C -> B -> C -> B -> C) ----
    static const int rates[6] = {1, 3, 9, 9, 3, 1};
    conv_mfma<FC><<<512, 256, 0, stream>>>(XpA, wt[0], bb[0], XpB, rates[0]);
    ushort_t* src = XpB;
    ushort_t* dst = XpC;
    for (int i = 1; i < 6; ++i) {
        conv_mfma<HID><<<512, 256, 0, stream>>>(src, wt[i], bb[i], dst, rates[i]);
        ushort_t* tmp = src; src = dst; dst = tmp;
    }

    // ---- head ----
    head_kernel<<<BATCH * NPTS, 64, 0, stream>>>(src, w_off, vertices, out);
}